// Round 1
// 635.532 us; speedup vs baseline: 1.0088x; 1.0088x over previous
//
#include <hip/hip_runtime.h>

// Bilinear 2x upsample, NHWC f32: in (8,256,256,64) -> out (8,512,512,64).
//
// v2 "row-pair": one thread per (b, k, ox, c4) where k is an INPUT row.
// Output rows 2k+1 and 2k+2 share the input row pair (k, k+1) with
// dy = 0.25 / 0.75, so ONE set of 4 tap loads feeds TWO output pixels
// (halves load-request traffic vs one-thread-per-output-pixel).
//   - Row 0 (dy=0 -> pure x-lerp of input row 0) is emitted by k==0 blocks.
//   - Row 511: k==255 has y1 clamped to 255 -> bo==t -> o1==t, automatically
//     equal to the reference (dy=0.25 with identical rows). No special case.
// All k-dependent branches are BLOCK-uniform (a 256-thread block spans only
// 16 ox values x 16 c4 at fixed k) -> no divergence.
//
// XCD swizzle: 65536 blocks = 8 contiguous chunks of 8192 = exactly one
// batch image b per XCD -> each XCD's private L2 streams its own 16.8 MB
// input slab once; no cross-XCD duplicate fetch. (65536 % 8 == 0 -> the
// simple chunk swizzle is bijective.)
//
// Nontemporal stores: output is write-once, never re-read -> keep L2 for
// the input taps.

constexpr int B     = 8;
constexpr int IN_H  = 256;
constexpr int IN_W  = 256;
constexpr int OUT_H = 512;
constexpr int OUT_W = 512;
constexpr int C4    = 16;                      // 64 channels / 4 floats
constexpr int TOTAL = B * IN_H * OUT_W * C4;   // 16,777,216 threads

typedef float v4f __attribute__((ext_vector_type(4)));

static __device__ __forceinline__ v4f vfma(float a, v4f x, v4f y) {
    v4f r;
    r.x = fmaf(a, x.x, y.x);
    r.y = fmaf(a, x.y, y.y);
    r.z = fmaf(a, x.z, y.z);
    r.w = fmaf(a, x.w, y.w);
    return r;
}

__global__ __launch_bounds__(256) void
bilerp2x_rowpair(const v4f* __restrict__ in, v4f* __restrict__ out) {
    // XCD-aware bijective remap: chunk c = bid & 7 -> blocks [c*8192, ...).
    int bid = (int)blockIdx.x;
    int swz = (bid & 7) * ((int)gridDim.x >> 3) + (bid >> 3);
    int i   = swz * 256 + (int)threadIdx.x;

    int c4 = i & (C4 - 1);
    int r1 = i >> 4;
    int ox = r1 & (OUT_W - 1);
    int r2 = r1 >> 9;                 // log2(OUT_W)
    int k  = r2 & (IN_H - 1);         // input row index; block-uniform
    int b  = r2 >> 8;                 // log2(IN_H)

    // x taps: sx = max((ox+0.5)*0.5 - 0.5, 0); exact in f32
    float sx = fmaxf((ox + 0.5f) * 0.5f - 0.5f, 0.0f);
    int   x0 = (int)sx;               // trunc == floor (sx >= 0)
    int   x1 = min(x0 + 1, IN_W - 1);
    float dx = sx - (float)x0;

    int y1   = min(k + 1, IN_H - 1);
    int row0 = (b * IN_H + k)  * IN_W;   // units of input pixels
    int row1 = (b * IN_H + y1) * IN_W;

    v4f lt = in[(row0 + x0) * C4 + c4];
    v4f rt = in[(row0 + x1) * C4 + c4];
    v4f lb = in[(row1 + x0) * C4 + c4];
    v4f rb = in[(row1 + x1) * C4 + c4];

    // x-lerps once, then two y-lerps sharing d = bo - t.
    v4f t  = vfma(dx, rt - lt, lt);
    v4f bo = vfma(dx, rb - lb, lb);
    v4f d  = bo - t;
    v4f o1 = vfma(0.25f, d, t);       // output row 2k+1
    v4f o2 = vfma(0.75f, d, t);       // output row 2k+2

    int out_r1 = ((b * OUT_H + (2 * k + 1)) * OUT_W + ox) * C4 + c4;

    __builtin_nontemporal_store(o1, &out[out_r1]);
    if (k < IN_H - 1)                                  // row 2k+2 <= 510
        __builtin_nontemporal_store(o2, &out[out_r1 + OUT_W * C4]);
    if (k == 0)                                        // row 0 = x-lerp(row0)
        __builtin_nontemporal_store(t, &out[out_r1 - OUT_W * C4]);
}

extern "C" void kernel_launch(void* const* d_in, const int* in_sizes, int n_in,
                              void* d_out, int out_size, void* d_ws, size_t ws_size,
                              hipStream_t stream) {
    (void)in_sizes; (void)n_in; (void)d_ws; (void)ws_size; (void)out_size;
    const v4f* in  = (const v4f*)d_in[0];
    v4f*       out = (v4f*)d_out;
    dim3 block(256);
    dim3 grid(TOTAL / 256);           // 65,536 blocks
    bilerp2x_rowpair<<<grid, block, 0, stream>>>(in, out);
}